// Round 14
// baseline (574.453 us; speedup 1.0000x reference)
//
#include <hip/hip_runtime.h>
#include <cstdint>

#define T 1024
#define H 2048
#define II 1408
#define E 32
#define TOPK 6
#define NGRP 4
#define GSZ 8
#define CAP 1024
#define CAPH 384

typedef __attribute__((ext_vector_type(8))) short short8;
typedef __attribute__((ext_vector_type(4))) float f32x4;
typedef __attribute__((ext_vector_type(2))) unsigned int u32x2;
typedef __attribute__((ext_vector_type(4))) unsigned short us4;

static __device__ __forceinline__ unsigned short f2bf(float f) {
    unsigned int u = __builtin_bit_cast(unsigned int, f);
    u += 0x7FFFu + ((u >> 16) & 1u);
    return (unsigned short)(u >> 16);
}

static __device__ __forceinline__ unsigned int cvtpk(float lo, float hi) {
    unsigned int r;
    asm("v_cvt_pk_bf16_f32 %0, %1, %2" : "=v"(r) : "v"(lo), "v"(hi));
    return r;
}

// Barrier that does NOT drain vmcnt: LDS visibility needs lgkmcnt(0) only;
// global loads land in private VGPRs and may stay in flight (T4).
#define KBAR() { \
        asm volatile("s_waitcnt lgkmcnt(0)" ::: "memory"); \
        __builtin_amdgcn_s_barrier(); \
        __builtin_amdgcn_sched_barrier(0); }

__global__ void prep_kernel(const float* __restrict__ x, unsigned short* __restrict__ xbf,
                            int* __restrict__ list, float* __restrict__ wts,
                            int* __restrict__ cnt) {
    int gid = blockIdx.x * blockDim.x + threadIdx.x;
    const int n4 = T * H / 4;
    if (gid < n4) {
        const float4 v = reinterpret_cast<const float4*>(x)[gid];
        us4 o;
        o.x = f2bf(v.x); o.y = f2bf(v.y); o.z = f2bf(v.z); o.w = f2bf(v.w);
        reinterpret_cast<us4*>(xbf)[gid] = o;
    }
    if (gid < T) { list[E * CAP + gid] = gid; wts[E * CAP + gid] = 1.0f; }
    if (gid < E + 1) cnt[gid] = (gid == E) ? T : 0;
}

__global__ __launch_bounds__(256) void router_kernel(
        const float* __restrict__ x, const float* __restrict__ gw,
        const float* __restrict__ bias, int* __restrict__ list,
        float* __restrict__ wts, int* __restrict__ cnt) {
    int t = blockIdx.x;
    int tid = threadIdx.x;
    int e = tid >> 3, p = tid & 7;
    const float4* xr = reinterpret_cast<const float4*>(x + (size_t)t * H);
    const float4* gr = reinterpret_cast<const float4*>(gw + (size_t)e * H);
    float part = 0.f;
    for (int q = 0; q < 64; ++q) {
        int idx = p * 64 + q;
        float4 a = xr[idx], b = gr[idx];
        part += a.x * b.x + a.y * b.y + a.z * b.z + a.w * b.w;
    }
    __shared__ float red[256];
    __shared__ float sc[E], sfc[E];
    red[tid] = part;
    __syncthreads();
    if (tid < E) {
        float s = 0.f;
        for (int j = 0; j < 8; ++j) s += red[tid * 8 + j];
        float sig = 1.f / (1.f + expf(-s));
        sc[tid] = sig;
        sfc[tid] = sig + bias[tid];
    }
    __syncthreads();
    if (tid == 0) {
        float gs[NGRP];
        for (int g = 0; g < NGRP; ++g) {
            float m1 = -INFINITY, m2 = -INFINITY;
            for (int j = 0; j < GSZ; ++j) {
                float v = sfc[g * GSZ + j];
                if (v > m1) { m2 = m1; m1 = v; }
                else if (v > m2) m2 = v;
            }
            gs[g] = m1 + m2;
        }
        int g1 = 0;
        for (int g = 1; g < NGRP; ++g) if (gs[g] > gs[g1]) g1 = g;
        int g2 = -1;
        for (int g = 0; g < NGRP; ++g) {
            if (g == g1) continue;
            if (g2 < 0 || gs[g] > gs[g2]) g2 = g;
        }
        int sel[TOPK];
        unsigned int usedmask = 0;
        float wsum = 0.f;
        for (int k = 0; k < TOPK; ++k) {
            float best = -INFINITY; int bi = -1;
            for (int ee = 0; ee < E; ++ee) {
                int g = ee >> 3;
                if (g != g1 && g != g2) continue;
                if (usedmask & (1u << ee)) continue;
                if (sfc[ee] > best) { best = sfc[ee]; bi = ee; }
            }
            usedmask |= (1u << bi);
            sel[k] = bi;
            wsum += sc[bi];
        }
        float fac = 2.5f / (wsum + 1e-20f);
        for (int k = 0; k < TOPK; ++k) {
            int ee = sel[k];
            int pos = atomicAdd(&cnt[ee], 1);
            list[ee * CAP + pos] = t;
            wts[ee * CAP + pos] = sc[ee] * fac;
        }
    }
}

// Pass A: h = silu(x@Wg)*(x@Wu). r9 structure; weight loads + h store are
// NON-TEMPORAL so the single-use weight stream stops evicting xbf from L2
// (the a-gathers are the latency-critical consumers of that cache).
__global__ __launch_bounds__(256, 2) void passA_kernel(
        const unsigned short* __restrict__ xbf,
        const float* __restrict__ wgate, const float* __restrict__ wup,
        const float* __restrict__ swgate, const float* __restrict__ swup,
        const int* __restrict__ list, const int* __restrict__ cnt,
        unsigned short* __restrict__ h) {
    int bx = blockIdx.x;
    int ve, start, end;
    if (bx < E) { ve = bx; start = 0; end = cnt[ve]; }
    else        { ve = E; start = (bx - E) * 256; end = start + 256; }
    if (start >= end) return;
    const int i0 = blockIdx.y * 32;
    const int tid = threadIdx.x, wave = tid >> 6, lane = tid & 63;
    const int lcol = lane & 15, lkg = lane >> 4;
    const int mat = tid >> 7;
    const int wcq = tid & 7;
    const int wkq = (tid >> 3) & 15;
    const float* G = (ve < E) ? wgate + (size_t)ve * H * II : swgate;
    const float* U = (ve < E) ? wup   + (size_t)ve * H * II : swup;
    const float* Wsrc = (mat ? U : G) + (size_t)(wkq * 4) * II + i0 + wcq * 4;
    __shared__ unsigned short lB[2][2][32 * 64];   // [buf][mat][row i][k]
    __shared__ int tokL[256];
    const int slotbase = (ve < E) ? ve * CAPH : E * CAPH;

#define LOADPF_A(PF, KS) { \
        const float* src = Wsrc + (size_t)((KS) * 64) * II; \
        _Pragma("unroll") \
        for (int q = 0; q < 4; ++q) \
            PF[q] = __builtin_nontemporal_load(reinterpret_cast<const f32x4*>(src + (size_t)q * II)); }

#define AISS_A(AR, KS) { \
        _Pragma("unroll") \
        for (int s = 0; s < 2; ++s) \
            _Pragma("unroll") \
            for (int m = 0; m < 4; ++m) \
                AR[s][m] = *reinterpret_cast<const short8*>(&xrow[m][(KS) * 64 + s * 32 + lkg * 8]); }

#define STAGE_A(BUF, PF) { \
        char* dst = (char*)&lB[BUF][mat][0]; \
        _Pragma("unroll") \
        for (int c = 0; c < 4; ++c) { \
            int ii = wcq * 4 + c; \
            unsigned int ad = ((unsigned)ii * 128 + (unsigned)wkq * 8) ^ (((unsigned)(ii & 7)) << 4); \
            u32x2 pk; \
            pk[0] = cvtpk(PF[0][c], PF[1][c]); \
            pk[1] = cvtpk(PF[2][c], PF[3][c]); \
            *reinterpret_cast<u32x2*>(dst + ad) = pk; \
        } }

#define ITER_A(KS, CUR, ACUR, ANXT, PFISS, PFSTG) { \
        if (wact && (KS) + 1 < 32) AISS_A(ANXT, (KS) + 1) \
        __builtin_amdgcn_sched_barrier(0); \
        if ((KS) + 2 < 32) LOADPF_A(PFISS, (KS) + 2) \
        __builtin_amdgcn_sched_barrier(0); \
        if (wact) { \
            const char* b0 = (const char*)&lB[CUR][0][0]; \
            const char* b1 = (const char*)&lB[CUR][1][0]; \
            __builtin_amdgcn_s_setprio(1); \
            _Pragma("unroll") \
            for (int s = 0; s < 2; ++s) { \
                _Pragma("unroll") \
                for (int n = 0; n < 2; ++n) { \
                    unsigned int ra = ((unsigned)(n * 16 + lcol) * 128 + (unsigned)(s * 64 + lkg * 16)) \
                                    ^ (((unsigned)(lcol & 7)) << 4); \
                    const short8 bg = *reinterpret_cast<const short8*>(b0 + ra); \
                    const short8 bu = *reinterpret_cast<const short8*>(b1 + ra); \
                    _Pragma("unroll") \
                    for (int m = 0; m < 4; ++m) { \
                        accg[m][n] = __builtin_amdgcn_mfma_f32_16x16x32_bf16(ACUR[s][m], bg, accg[m][n], 0, 0, 0); \
                        accu[m][n] = __builtin_amdgcn_mfma_f32_16x16x32_bf16(ACUR[s][m], bu, accu[m][n], 0, 0, 0); \
                    } \
                } \
            } \
            __builtin_amdgcn_s_setprio(0); \
        } \
        if ((KS) + 1 < 32) STAGE_A((CUR) ^ 1, PFSTG) \
        KBAR() }

    for (int m0 = start; m0 < end; m0 += 256) {
        int msize = min(256, end - m0);
        tokL[tid] = (tid < msize) ? list[ve * CAP + m0 + tid] : 0;
        f32x4 accg[4][2] = {};
        f32x4 accu[4][2] = {};
        f32x4 pfA[4], pfB[4];
        short8 aA[2][4], aB[2][4];
        __syncthreads();
        const unsigned short* xrow[4];
        #pragma unroll
        for (int m = 0; m < 4; ++m)
            xrow[m] = xbf + (size_t)tokL[wave * 64 + m * 16 + lcol] * H;
        bool wact = (wave * 64) < msize;
        LOADPF_A(pfA, 0)
        if (wact) AISS_A(aA, 0)
        STAGE_A(0, pfA)
        LOADPF_A(pfB, 1)
        KBAR()

        #pragma unroll 1
        for (int ks = 0; ks < 32; ks += 2) {
            ITER_A(ks, 0, aA, aB, pfA, pfB)
            ITER_A(ks + 1, 1, aB, aA, pfB, pfA)
        }
        if (wact) {
            #pragma unroll
            for (int m = 0; m < 4; ++m)
                #pragma unroll
                for (int n = 0; n < 2; ++n)
                    #pragma unroll
                    for (int r = 0; r < 4; ++r) {
                        int rowl = wave * 64 + m * 16 + lkg * 4 + r;
                        int pos = m0 + rowl;
                        bool ok = (rowl < msize) && !(ve < E && pos >= CAPH);
                        float gv = accg[m][n][r], uv = accu[m][n][r];
                        float hv = gv / (1.f + expf(-gv)) * uv;
                        if (ok)
                            __builtin_nontemporal_store(f2bf(hv),
                                &h[(size_t)(slotbase + pos) * II + i0 + n * 16 + lcol]);
                    }
        }
        __syncthreads();
    }
#undef ITER_A
#undef STAGE_A
#undef AISS_A
#undef LOADPF_A
}

// Pass B: out[tok] += wt * (h @ Wdown). r9 structure; weight + h loads NT.
__global__ __launch_bounds__(256, 2) void passB_kernel(
        const unsigned short* __restrict__ h,
        const float* __restrict__ wdown, const float* __restrict__ swdown,
        const int* __restrict__ list, const float* __restrict__ wts,
        const int* __restrict__ cnt, float* __restrict__ out) {
    int bx = blockIdx.x;
    int ve, start, end;
    if (bx < E) { ve = bx; start = 0; end = cnt[ve]; }
    else        { ve = E; start = (bx - E) * 256; end = start + 256; }
    if (start >= end) return;
    const float* W = (ve < E) ? wdown + (size_t)ve * II * H : swdown;
    const int n0 = blockIdx.y * 64;
    const int tid = threadIdx.x, wave = tid >> 6, lane = tid & 63;
    const int lcol = lane & 15, lkg = lane >> 4;
    const int wnq = tid & 15;
    const int wkq = tid >> 4;
    const float* Wsrc = W + (size_t)(wkq * 4) * H + n0 + wnq * 4;
    __shared__ unsigned short lW[2][64 * 64];
    __shared__ int tokL[256];
    __shared__ float wtL[256];
    const int slotbase = (ve < E) ? ve * CAPH : E * CAPH;
    const int NS = II / 64;  // 22

#define LOADPF_B(PF, KS) { \
        const float* src = Wsrc + (size_t)((KS) * 64) * H; \
        _Pragma("unroll") \
        for (int q = 0; q < 4; ++q) \
            PF[q] = __builtin_nontemporal_load(reinterpret_cast<const f32x4*>(src + (size_t)q * H)); }

#define AISS_B(AR, KS) { \
        _Pragma("unroll") \
        for (int s = 0; s < 2; ++s) \
            _Pragma("unroll") \
            for (int m = 0; m < 4; ++m) \
                AR[s][m] = __builtin_nontemporal_load( \
                    reinterpret_cast<const short8*>(&hrow[m][(KS) * 64 + s * 32 + lkg * 8])); }

#define STAGE_B(BUF, PF) { \
        char* dst = (char*)&lW[BUF][0]; \
        _Pragma("unroll") \
        for (int c = 0; c < 4; ++c) { \
            int nn = wnq * 4 + c; \
            unsigned int ad = ((unsigned)nn * 128 + (unsigned)wkq * 8) ^ (((unsigned)(nn & 7)) << 4); \
            u32x2 pk; \
            pk[0] = cvtpk(PF[0][c], PF[1][c]); \
            pk[1] = cvtpk(PF[2][c], PF[3][c]); \
            *reinterpret_cast<u32x2*>(dst + ad) = pk; \
        } }

#define ITER_B(KS, CUR, ACUR, ANXT, PFISS, PFSTG) { \
        if (wact && (KS) + 1 < NS) AISS_B(ANXT, (KS) + 1) \
        __builtin_amdgcn_sched_barrier(0); \
        if ((KS) + 2 < NS) LOADPF_B(PFISS, (KS) + 2) \
        __builtin_amdgcn_sched_barrier(0); \
        if (wact) { \
            const char* bw0 = (const char*)&lW[CUR][0]; \
            __builtin_amdgcn_s_setprio(1); \
            _Pragma("unroll") \
            for (int s = 0; s < 2; ++s) { \
                _Pragma("unroll") \
                for (int n = 0; n < 4; ++n) { \
                    unsigned int ra = ((unsigned)(n * 16 + lcol) * 128 + (unsigned)(s * 64 + lkg * 16)) \
                                    ^ (((unsigned)(lcol & 7)) << 4); \
                    const short8 b = *reinterpret_cast<const short8*>(bw0 + ra); \
                    _Pragma("unroll") \
                    for (int m = 0; m < 4; ++m) \
                        acc[m][n] = __builtin_amdgcn_mfma_f32_16x16x32_bf16(ACUR[s][m], b, acc[m][n], 0, 0, 0); \
                } \
            } \
            __builtin_amdgcn_s_setprio(0); \
        } \
        if ((KS) + 1 < NS) STAGE_B((CUR) ^ 1, PFSTG) \
        KBAR() }

    for (int m0 = start; m0 < end; m0 += 256) {
        int msize = min(256, end - m0);
        tokL[tid] = (tid < msize) ? list[ve * CAP + m0 + tid] : 0;
        wtL[tid]  = (tid < msize) ? wts[ve * CAP + m0 + tid] : 0.f;
        f32x4 acc[4][4] = {};
        f32x4 pfA[4], pfB[4];
        short8 aA[2][4], aB[2][4];
        __syncthreads();
        const unsigned short* hrow[4];
        #pragma unroll
        for (int m = 0; m < 4; ++m)
            hrow[m] = h + (size_t)(slotbase + m0 + wave * 64 + m * 16 + lcol) * II;
        bool wact = (wave * 64) < msize;
        LOADPF_B(pfA, 0)
        if (wact) AISS_B(aA, 0)
        STAGE_B(0, pfA)
        LOADPF_B(pfB, 1)
        KBAR()

        #pragma unroll 1
        for (int ks = 0; ks < NS; ks += 2) {
            ITER_B(ks, 0, aA, aB, pfA, pfB)
            ITER_B(ks + 1, 1, aB, aA, pfB, pfA)
        }
        if (wact) {
            #pragma unroll
            for (int m = 0; m < 4; ++m)
                #pragma unroll
                for (int n = 0; n < 4; ++n)
                    #pragma unroll
                    for (int r = 0; r < 4; ++r) {
                        int rowl = wave * 64 + m * 16 + lkg * 4 + r;
                        if (rowl < msize) {
                            int tok = tokL[rowl];
                            float wv = wtL[rowl];
                            unsafeAtomicAdd(&out[(size_t)tok * H + n0 + n * 16 + lcol],
                                            acc[m][n][r] * wv);
                        }
                    }
        }
        __syncthreads();
    }
#undef ITER_B
#undef STAGE_B
#undef AISS_B
#undef LOADPF_B
}

extern "C" void kernel_launch(void* const* d_in, const int* in_sizes, int n_in,
                              void* d_out, int out_size, void* d_ws, size_t ws_size,
                              hipStream_t stream) {
    const float* x       = (const float*)d_in[0];
    const float* gate_w  = (const float*)d_in[1];
    const float* e_bias  = (const float*)d_in[2];
    const float* w_gate  = (const float*)d_in[3];
    const float* w_up    = (const float*)d_in[4];
    const float* w_down  = (const float*)d_in[5];
    const float* sw_gate = (const float*)d_in[6];
    const float* sw_up   = (const float*)d_in[7];
    const float* sw_down = (const float*)d_in[8];
    float* out = (float*)d_out;

    char* ws = (char*)d_ws;
    unsigned short* xbf = (unsigned short*)ws;                       // 4 MB
    int*   list = (int*)(ws + 4194304);                              // 132 KB
    float* wts  = (float*)(ws + 4194304 + 135168);                   // 132 KB
    int*   cnt  = (int*)(ws + 4194304 + 2 * 135168);                 // 256 B
    unsigned short* h = (unsigned short*)(ws + 4194304 + 2 * 135168 + 256); // ~37.5 MB

    hipMemsetAsync(d_out, 0, (size_t)T * H * sizeof(float), stream);
    prep_kernel<<<dim3(2048), dim3(256), 0, stream>>>(x, xbf, list, wts, cnt);
    router_kernel<<<dim3(T), dim3(256), 0, stream>>>(x, gate_w, e_bias, list, wts, cnt);
    passA_kernel<<<dim3(36, 44), dim3(256), 0, stream>>>(xbf, w_gate, w_up, sw_gate, sw_up, list, cnt, h);
    passB_kernel<<<dim3(36, 32), dim3(256), 0, stream>>>(h, w_down, sw_down, list, wts, cnt, out);
}

// Round 15
// 499.779 us; speedup vs baseline: 1.1494x; 1.1494x over previous
//
#include <hip/hip_runtime.h>
#include <cstdint>

#define T 1024
#define H 2048
#define II 1408
#define E 32
#define TOPK 6
#define NGRP 4
#define GSZ 8
#define CAP 1024
#define CAPH 384

typedef __attribute__((ext_vector_type(8))) short short8;
typedef __attribute__((ext_vector_type(4))) float f32x4;
typedef __attribute__((ext_vector_type(2))) unsigned int u32x2;
typedef __attribute__((ext_vector_type(4))) unsigned short us4;

static __device__ __forceinline__ unsigned short f2bf(float f) {
    unsigned int u = __builtin_bit_cast(unsigned int, f);
    u += 0x7FFFu + ((u >> 16) & 1u);
    return (unsigned short)(u >> 16);
}

static __device__ __forceinline__ unsigned int cvtpk(float lo, float hi) {
    unsigned int r;
    asm("v_cvt_pk_bf16_f32 %0, %1, %2" : "=v"(r) : "v"(lo), "v"(hi));
    return r;
}

// Barrier that does NOT drain vmcnt: LDS visibility needs lgkmcnt(0) only;
// global loads land in private VGPRs and may stay in flight (T4).
#define KBAR() { \
        asm volatile("s_waitcnt lgkmcnt(0)" ::: "memory"); \
        __builtin_amdgcn_s_barrier(); \
        __builtin_amdgcn_sched_barrier(0); }

__global__ void prep_kernel(const float* __restrict__ x, unsigned short* __restrict__ xbf,
                            int* __restrict__ list, float* __restrict__ wts,
                            int* __restrict__ cnt) {
    int gid = blockIdx.x * blockDim.x + threadIdx.x;
    const int n4 = T * H / 4;
    if (gid < n4) {
        const float4 v = reinterpret_cast<const float4*>(x)[gid];
        us4 o;
        o.x = f2bf(v.x); o.y = f2bf(v.y); o.z = f2bf(v.z); o.w = f2bf(v.w);
        reinterpret_cast<us4*>(xbf)[gid] = o;
    }
    if (gid < T) { list[E * CAP + gid] = gid; wts[E * CAP + gid] = 1.0f; }
    if (gid < E + 1) cnt[gid] = (gid == E) ? T : 0;
}

__global__ __launch_bounds__(256) void router_kernel(
        const float* __restrict__ x, const float* __restrict__ gw,
        const float* __restrict__ bias, int* __restrict__ list,
        float* __restrict__ wts, int* __restrict__ cnt) {
    int t = blockIdx.x;
    int tid = threadIdx.x;
    int e = tid >> 3, p = tid & 7;
    const float4* xr = reinterpret_cast<const float4*>(x + (size_t)t * H);
    const float4* gr = reinterpret_cast<const float4*>(gw + (size_t)e * H);
    float part = 0.f;
    for (int q = 0; q < 64; ++q) {
        int idx = p * 64 + q;
        float4 a = xr[idx], b = gr[idx];
        part += a.x * b.x + a.y * b.y + a.z * b.z + a.w * b.w;
    }
    __shared__ float red[256];
    __shared__ float sc[E], sfc[E];
    red[tid] = part;
    __syncthreads();
    if (tid < E) {
        float s = 0.f;
        for (int j = 0; j < 8; ++j) s += red[tid * 8 + j];
        float sig = 1.f / (1.f + expf(-s));
        sc[tid] = sig;
        sfc[tid] = sig + bias[tid];
    }
    __syncthreads();
    if (tid == 0) {
        float gs[NGRP];
        for (int g = 0; g < NGRP; ++g) {
            float m1 = -INFINITY, m2 = -INFINITY;
            for (int j = 0; j < GSZ; ++j) {
                float v = sfc[g * GSZ + j];
                if (v > m1) { m2 = m1; m1 = v; }
                else if (v > m2) m2 = v;
            }
            gs[g] = m1 + m2;
        }
        int g1 = 0;
        for (int g = 1; g < NGRP; ++g) if (gs[g] > gs[g1]) g1 = g;
        int g2 = -1;
        for (int g = 0; g < NGRP; ++g) {
            if (g == g1) continue;
            if (g2 < 0 || gs[g] > gs[g2]) g2 = g;
        }
        int sel[TOPK];
        unsigned int usedmask = 0;
        float wsum = 0.f;
        for (int k = 0; k < TOPK; ++k) {
            float best = -INFINITY; int bi = -1;
            for (int ee = 0; ee < E; ++ee) {
                int g = ee >> 3;
                if (g != g1 && g != g2) continue;
                if (usedmask & (1u << ee)) continue;
                if (sfc[ee] > best) { best = sfc[ee]; bi = ee; }
            }
            usedmask |= (1u << bi);
            sel[k] = bi;
            wsum += sc[bi];
        }
        float fac = 2.5f / (wsum + 1e-20f);
        for (int k = 0; k < TOPK; ++k) {
            int ee = sel[k];
            int pos = atomicAdd(&cnt[ee], 1);
            list[ee * CAP + pos] = t;
            wts[ee * CAP + pos] = sc[ee] * fac;
        }
    }
}

// Pass A: h = silu(x@Wg)*(x@Wu). r9 structure; WEIGHT loads non-temporal
// (single-use stream must not evict xbf from L2); h store is normal cached
// (h is 32x-reused by passB — r14 lesson).
__global__ __launch_bounds__(256, 2) void passA_kernel(
        const unsigned short* __restrict__ xbf,
        const float* __restrict__ wgate, const float* __restrict__ wup,
        const float* __restrict__ swgate, const float* __restrict__ swup,
        const int* __restrict__ list, const int* __restrict__ cnt,
        unsigned short* __restrict__ h) {
    int bx = blockIdx.x;
    int ve, start, end;
    if (bx < E) { ve = bx; start = 0; end = cnt[ve]; }
    else        { ve = E; start = (bx - E) * 256; end = start + 256; }
    if (start >= end) return;
    const int i0 = blockIdx.y * 32;
    const int tid = threadIdx.x, wave = tid >> 6, lane = tid & 63;
    const int lcol = lane & 15, lkg = lane >> 4;
    const int mat = tid >> 7;
    const int wcq = tid & 7;
    const int wkq = (tid >> 3) & 15;
    const float* G = (ve < E) ? wgate + (size_t)ve * H * II : swgate;
    const float* U = (ve < E) ? wup   + (size_t)ve * H * II : swup;
    const float* Wsrc = (mat ? U : G) + (size_t)(wkq * 4) * II + i0 + wcq * 4;
    __shared__ unsigned short lB[2][2][32 * 64];   // [buf][mat][row i][k]
    __shared__ int tokL[256];
    const int slotbase = (ve < E) ? ve * CAPH : E * CAPH;

#define LOADPF_A(PF, KS) { \
        const float* src = Wsrc + (size_t)((KS) * 64) * II; \
        _Pragma("unroll") \
        for (int q = 0; q < 4; ++q) \
            PF[q] = __builtin_nontemporal_load(reinterpret_cast<const f32x4*>(src + (size_t)q * II)); }

#define AISS_A(AR, KS) { \
        _Pragma("unroll") \
        for (int s = 0; s < 2; ++s) \
            _Pragma("unroll") \
            for (int m = 0; m < 4; ++m) \
                AR[s][m] = *reinterpret_cast<const short8*>(&xrow[m][(KS) * 64 + s * 32 + lkg * 8]); }

#define STAGE_A(BUF, PF) { \
        char* dst = (char*)&lB[BUF][mat][0]; \
        _Pragma("unroll") \
        for (int c = 0; c < 4; ++c) { \
            int ii = wcq * 4 + c; \
            unsigned int ad = ((unsigned)ii * 128 + (unsigned)wkq * 8) ^ (((unsigned)(ii & 7)) << 4); \
            u32x2 pk; \
            pk[0] = cvtpk(PF[0][c], PF[1][c]); \
            pk[1] = cvtpk(PF[2][c], PF[3][c]); \
            *reinterpret_cast<u32x2*>(dst + ad) = pk; \
        } }

#define ITER_A(KS, CUR, ACUR, ANXT, PFISS, PFSTG) { \
        if (wact && (KS) + 1 < 32) AISS_A(ANXT, (KS) + 1) \
        __builtin_amdgcn_sched_barrier(0); \
        if ((KS) + 2 < 32) LOADPF_A(PFISS, (KS) + 2) \
        __builtin_amdgcn_sched_barrier(0); \
        if (wact) { \
            const char* b0 = (const char*)&lB[CUR][0][0]; \
            const char* b1 = (const char*)&lB[CUR][1][0]; \
            __builtin_amdgcn_s_setprio(1); \
            _Pragma("unroll") \
            for (int s = 0; s < 2; ++s) { \
                _Pragma("unroll") \
                for (int n = 0; n < 2; ++n) { \
                    unsigned int ra = ((unsigned)(n * 16 + lcol) * 128 + (unsigned)(s * 64 + lkg * 16)) \
                                    ^ (((unsigned)(lcol & 7)) << 4); \
                    const short8 bg = *reinterpret_cast<const short8*>(b0 + ra); \
                    const short8 bu = *reinterpret_cast<const short8*>(b1 + ra); \
                    _Pragma("unroll") \
                    for (int m = 0; m < 4; ++m) { \
                        accg[m][n] = __builtin_amdgcn_mfma_f32_16x16x32_bf16(ACUR[s][m], bg, accg[m][n], 0, 0, 0); \
                        accu[m][n] = __builtin_amdgcn_mfma_f32_16x16x32_bf16(ACUR[s][m], bu, accu[m][n], 0, 0, 0); \
                    } \
                } \
            } \
            __builtin_amdgcn_s_setprio(0); \
        } \
        if ((KS) + 1 < 32) STAGE_A((CUR) ^ 1, PFSTG) \
        KBAR() }

    for (int m0 = start; m0 < end; m0 += 256) {
        int msize = min(256, end - m0);
        tokL[tid] = (tid < msize) ? list[ve * CAP + m0 + tid] : 0;
        f32x4 accg[4][2] = {};
        f32x4 accu[4][2] = {};
        f32x4 pfA[4], pfB[4];
        short8 aA[2][4], aB[2][4];
        __syncthreads();
        const unsigned short* xrow[4];
        #pragma unroll
        for (int m = 0; m < 4; ++m)
            xrow[m] = xbf + (size_t)tokL[wave * 64 + m * 16 + lcol] * H;
        bool wact = (wave * 64) < msize;
        LOADPF_A(pfA, 0)
        if (wact) AISS_A(aA, 0)
        STAGE_A(0, pfA)
        LOADPF_A(pfB, 1)
        KBAR()

        #pragma unroll 1
        for (int ks = 0; ks < 32; ks += 2) {
            ITER_A(ks, 0, aA, aB, pfA, pfB)
            ITER_A(ks + 1, 1, aB, aA, pfB, pfA)
        }
        if (wact) {
            #pragma unroll
            for (int m = 0; m < 4; ++m)
                #pragma unroll
                for (int n = 0; n < 2; ++n)
                    #pragma unroll
                    for (int r = 0; r < 4; ++r) {
                        int rowl = wave * 64 + m * 16 + lkg * 4 + r;
                        int pos = m0 + rowl;
                        bool ok = (rowl < msize) && !(ve < E && pos >= CAPH);
                        float gv = accg[m][n][r], uv = accu[m][n][r];
                        float hv = gv / (1.f + expf(-gv)) * uv;
                        if (ok)
                            h[(size_t)(slotbase + pos) * II + i0 + n * 16 + lcol] = f2bf(hv);
                    }
        }
        __syncthreads();
    }
#undef ITER_A
#undef STAGE_A
#undef AISS_A
#undef LOADPF_A
}

// Pass B: out[tok] += wt * (h @ Wdown). Weight loads NT; h loads normal
// cached (each expert's h rows are reused by its 32 n-tile blocks).
__global__ __launch_bounds__(256, 2) void passB_kernel(
        const unsigned short* __restrict__ h,
        const float* __restrict__ wdown, const float* __restrict__ swdown,
        const int* __restrict__ list, const float* __restrict__ wts,
        const int* __restrict__ cnt, float* __restrict__ out) {
    int bx = blockIdx.x;
    int ve, start, end;
    if (bx < E) { ve = bx; start = 0; end = cnt[ve]; }
    else        { ve = E; start = (bx - E) * 256; end = start + 256; }
    if (start >= end) return;
    const float* W = (ve < E) ? wdown + (size_t)ve * II * H : swdown;
    const int n0 = blockIdx.y * 64;
    const int tid = threadIdx.x, wave = tid >> 6, lane = tid & 63;
    const int lcol = lane & 15, lkg = lane >> 4;
    const int wnq = tid & 15;
    const int wkq = tid >> 4;
    const float* Wsrc = W + (size_t)(wkq * 4) * H + n0 + wnq * 4;
    __shared__ unsigned short lW[2][64 * 64];
    __shared__ int tokL[256];
    __shared__ float wtL[256];
    const int slotbase = (ve < E) ? ve * CAPH : E * CAPH;
    const int NS = II / 64;  // 22

#define LOADPF_B(PF, KS) { \
        const float* src = Wsrc + (size_t)((KS) * 64) * H; \
        _Pragma("unroll") \
        for (int q = 0; q < 4; ++q) \
            PF[q] = __builtin_nontemporal_load(reinterpret_cast<const f32x4*>(src + (size_t)q * H)); }

#define AISS_B(AR, KS) { \
        _Pragma("unroll") \
        for (int s = 0; s < 2; ++s) \
            _Pragma("unroll") \
            for (int m = 0; m < 4; ++m) \
                AR[s][m] = *reinterpret_cast<const short8*>(&hrow[m][(KS) * 64 + s * 32 + lkg * 8]); }

#define STAGE_B(BUF, PF) { \
        char* dst = (char*)&lW[BUF][0]; \
        _Pragma("unroll") \
        for (int c = 0; c < 4; ++c) { \
            int nn = wnq * 4 + c; \
            unsigned int ad = ((unsigned)nn * 128 + (unsigned)wkq * 8) ^ (((unsigned)(nn & 7)) << 4); \
            u32x2 pk; \
            pk[0] = cvtpk(PF[0][c], PF[1][c]); \
            pk[1] = cvtpk(PF[2][c], PF[3][c]); \
            *reinterpret_cast<u32x2*>(dst + ad) = pk; \
        } }

#define ITER_B(KS, CUR, ACUR, ANXT, PFISS, PFSTG) { \
        if (wact && (KS) + 1 < NS) AISS_B(ANXT, (KS) + 1) \
        __builtin_amdgcn_sched_barrier(0); \
        if ((KS) + 2 < NS) LOADPF_B(PFISS, (KS) + 2) \
        __builtin_amdgcn_sched_barrier(0); \
        if (wact) { \
            const char* bw0 = (const char*)&lW[CUR][0]; \
            __builtin_amdgcn_s_setprio(1); \
            _Pragma("unroll") \
            for (int s = 0; s < 2; ++s) { \
                _Pragma("unroll") \
                for (int n = 0; n < 4; ++n) { \
                    unsigned int ra = ((unsigned)(n * 16 + lcol) * 128 + (unsigned)(s * 64 + lkg * 16)) \
                                    ^ (((unsigned)(lcol & 7)) << 4); \
                    const short8 b = *reinterpret_cast<const short8*>(bw0 + ra); \
                    _Pragma("unroll") \
                    for (int m = 0; m < 4; ++m) \
                        acc[m][n] = __builtin_amdgcn_mfma_f32_16x16x32_bf16(ACUR[s][m], b, acc[m][n], 0, 0, 0); \
                } \
            } \
            __builtin_amdgcn_s_setprio(0); \
        } \
        if ((KS) + 1 < NS) STAGE_B((CUR) ^ 1, PFSTG) \
        KBAR() }

    for (int m0 = start; m0 < end; m0 += 256) {
        int msize = min(256, end - m0);
        tokL[tid] = (tid < msize) ? list[ve * CAP + m0 + tid] : 0;
        wtL[tid]  = (tid < msize) ? wts[ve * CAP + m0 + tid] : 0.f;
        f32x4 acc[4][4] = {};
        f32x4 pfA[4], pfB[4];
        short8 aA[2][4], aB[2][4];
        __syncthreads();
        const unsigned short* hrow[4];
        #pragma unroll
        for (int m = 0; m < 4; ++m)
            hrow[m] = h + (size_t)(slotbase + m0 + wave * 64 + m * 16 + lcol) * II;
        bool wact = (wave * 64) < msize;
        LOADPF_B(pfA, 0)
        if (wact) AISS_B(aA, 0)
        STAGE_B(0, pfA)
        LOADPF_B(pfB, 1)
        KBAR()

        #pragma unroll 1
        for (int ks = 0; ks < NS; ks += 2) {
            ITER_B(ks, 0, aA, aB, pfA, pfB)
            ITER_B(ks + 1, 1, aB, aA, pfB, pfA)
        }
        if (wact) {
            #pragma unroll
            for (int m = 0; m < 4; ++m)
                #pragma unroll
                for (int n = 0; n < 4; ++n)
                    #pragma unroll
                    for (int r = 0; r < 4; ++r) {
                        int rowl = wave * 64 + m * 16 + lkg * 4 + r;
                        if (rowl < msize) {
                            int tok = tokL[rowl];
                            float wv = wtL[rowl];
                            unsafeAtomicAdd(&out[(size_t)tok * H + n0 + n * 16 + lcol],
                                            acc[m][n][r] * wv);
                        }
                    }
        }
        __syncthreads();
    }
#undef ITER_B
#undef STAGE_B
#undef AISS_B
#undef LOADPF_B
}

extern "C" void kernel_launch(void* const* d_in, const int* in_sizes, int n_in,
                              void* d_out, int out_size, void* d_ws, size_t ws_size,
                              hipStream_t stream) {
    const float* x       = (const float*)d_in[0];
    const float* gate_w  = (const float*)d_in[1];
    const float* e_bias  = (const float*)d_in[2];
    const float* w_gate  = (const float*)d_in[3];
    const float* w_up    = (const float*)d_in[4];
    const float* w_down  = (const float*)d_in[5];
    const float* sw_gate = (const float*)d_in[6];
    const float* sw_up   = (const float*)d_in[7];
    const float* sw_down = (const float*)d_in[8];
    float* out = (float*)d_out;

    char* ws = (char*)d_ws;
    unsigned short* xbf = (unsigned short*)ws;                       // 4 MB
    int*   list = (int*)(ws + 4194304);                              // 132 KB
    float* wts  = (float*)(ws + 4194304 + 135168);                   // 132 KB
    int*   cnt  = (int*)(ws + 4194304 + 2 * 135168);                 // 256 B
    unsigned short* h = (unsigned short*)(ws + 4194304 + 2 * 135168 + 256); // ~37.5 MB

    hipMemsetAsync(d_out, 0, (size_t)T * H * sizeof(float), stream);
    prep_kernel<<<dim3(2048), dim3(256), 0, stream>>>(x, xbf, list, wts, cnt);
    router_kernel<<<dim3(T), dim3(256), 0, stream>>>(x, gate_w, e_bias, list, wts, cnt);
    passA_kernel<<<dim3(36, 44), dim3(256), 0, stream>>>(xbf, w_gate, w_up, sw_gate, sw_up, list, cnt, h);
    passB_kernel<<<dim3(36, 32), dim3(256), 0, stream>>>(h, w_down, sw_down, list, wts, cnt, out);
}